// Round 3
// baseline (177.773 us; speedup 1.0000x reference)
//
#include <hip/hip_runtime.h>

#define CINC 64
#define COUT 64
#define HH 32
#define WW 32
#define BB 16

typedef __attribute__((ext_vector_type(8))) short short8;
typedef __attribute__((ext_vector_type(4))) float floatx4;

__device__ __forceinline__ unsigned short f2bf(float f) {
    union { float f; unsigned int u; } c; c.f = f;
    unsigned int r = (c.u + 0x7FFFu + ((c.u >> 16) & 1u)) >> 16;
    return (unsigned short)r;
}

// W3 layout: [split(8)][tap(9)][s(2)][oc(64)][q(4)][e(8)] bf16,
// element = sw[oc][cin][g][kh][kw]*sc[oc][cin], k = s*32+q*8+e, cin = split*8 + k/8, g = k%8
__global__ __launch_bounds__(256) void wt_kernel(const float* __restrict__ sw,
                                                 const float* __restrict__ sc,
                                                 short* __restrict__ W3) {
    int idx = blockIdx.x * blockDim.x + threadIdx.x;
    const int total = 8 * 9 * 2 * 64 * 4 * 8;   // 294,912
    if (idx >= total) return;
    int e = idx & 7;
    int q = (idx >> 3) & 3;
    int oc = (idx >> 5) & 63;
    int s = (idx >> 11) & 1;
    int tap = (idx >> 12) % 9;
    int split = (idx >> 12) / 9;
    int k = s * 32 + q * 8 + e;
    int cin = split * 8 + (k >> 3);
    int g = k & 7;
    int kh = tap / 3, kw = tap % 3;
    float w = sw[(((oc * CINC + cin) * 8 + g) * 3 + kh) * 3 + kw] * sc[oc * CINC + cin];
    W3[idx] = (short)f2bf(w);
}

__global__ __launch_bounds__(256) void zero_kernel(float4* __restrict__ out) {
    int idx = blockIdx.x * blockDim.x + threadIdx.x;
    out[idx] = make_float4(0.f, 0.f, 0.f, 0.f);
}

// Fused bases + implicit-GEMM conv.
// Grid: 1024 = 8 splits (major) x 128 m-blocks. Block: 4 waves.
// m-block: batch b, output rows h0..h0+3 (128 pixels). Wave w -> row h0+w, 32m x 64n.
__global__ __launch_bounds__(256, 4) void conv_kernel(const float* __restrict__ xin,
                                                      const short* __restrict__ W3,
                                                      float* __restrict__ out) {
    __shared__ short A[6 * 34 * 64];   // 26,112 B: [r(6)][x(34)][slot(8)][e(8)], slot = kg^(x&7)

    const int split = blockIdx.x >> 7;
    const int mb = blockIdx.x & 127;
    const int b = mb >> 3;
    const int h0 = (mb & 7) * 4;
    const int t = threadIdx.x;
    const int wave = t >> 6;
    const int lane = t & 63;
    const int l15 = lane & 15;
    const int q = lane >> 4;
    const int cin0 = split * 8;

    // ---- prefetch first B fragments (no LDS dependency) ----
    const short* Wb = W3 + (size_t)split * 9 * 4096;
    short8 bq[4], bqn[4];
#pragma unroll
    for (int nt = 0; nt < 4; ++nt)
        bqn[nt] = *(const short8*)(Wb + (nt * 16 + l15) * 32 + q * 8);

    // ---- stage A: compute bf16 B-spline bases directly into LDS ----
    for (int u = t; u < 6 * 34 * 8; u += 256) {   // 1632 items, x-innermost (coalesced)
        int x34 = u % 34;
        int rc = u / 34;
        int cl = rc & 7;
        int r = rc >> 3;
        int y = h0 + r;                            // padded row index
        float v = 0.0f;
        if (y >= 1 && y <= HH && x34 >= 1 && x34 <= WW)
            v = xin[((b * CINC + cin0 + cl) * HH + (y - 1)) * WW + (x34 - 1)];
        // closed-form uniform cubic B-spline: cell c, frac f; active bases j = c-3..c
        float sv = fmaf(v, 2.5f, 5.5f);            // (v - t0)/h, t0 = -2.2, h = 0.4
        float cf = floorf(sv);
        int c = (int)cf;
        float f = sv - cf;
        float f2 = f * f, f3 = f2 * f;
        float omf = 1.0f - f;
        float w0 = f3 * (1.0f / 6.0f);                                   // bs[c]
        float w1 = (1.0f + 3.0f * f + 3.0f * f2 - 3.0f * f3) * (1.0f / 6.0f); // bs[c-1]
        float w2 = (4.0f - 6.0f * f2 + 3.0f * f3) * (1.0f / 6.0f);       // bs[c-2]
        float w3 = (omf * omf * omf) * (1.0f / 6.0f);                    // bs[c-3]
        short o8[8];
#pragma unroll
        for (int j = 0; j < 8; ++j) {
            float bj = (j == c) ? w0 : (j == c - 1) ? w1 : (j == c - 2) ? w2
                       : (j == c - 3) ? w3 : 0.0f;
            o8[j] = (short)f2bf(bj);
        }
        *(int4*)&A[(r * 34 + x34) * 64 + ((cl ^ (x34 & 7)) * 8)] = *(const int4*)o8;
    }
    __syncthreads();

    floatx4 acc[2][4];
#pragma unroll
    for (int mt = 0; mt < 2; ++mt)
#pragma unroll
        for (int nt = 0; nt < 4; ++nt) acc[mt][nt] = (floatx4)0.f;

    // ---- main loop: 18 steps = 9 taps x 2 k-halves, 1-step B prefetch ----
#pragma unroll
    for (int ts = 0; ts < 18; ++ts) {
        const int tap = ts >> 1, s = ts & 1;
        const int kh = tap / 3, kw = tap % 3;
#pragma unroll
        for (int nt = 0; nt < 4; ++nt) bq[nt] = bqn[nt];
        if (ts < 17) {
            const int tsn = ts + 1;
            const short* wp = Wb + (size_t)(tsn) * 2048;
#pragma unroll
            for (int nt = 0; nt < 4; ++nt)
                bqn[nt] = *(const short8*)(wp + (nt * 16 + l15) * 32 + q * 8);
        }
#pragma unroll
        for (int mt = 0; mt < 2; ++mt) {
            const int xi = mt * 16 + l15 + kw;
            short8 aF = *(const short8*)&A[(((wave + kh) * 34 + xi) * 64) +
                                           (((s * 4 + q) ^ (xi & 7)) * 8)];
#pragma unroll
            for (int nt = 0; nt < 4; ++nt)
                acc[mt][nt] = __builtin_amdgcn_mfma_f32_16x16x32_bf16(aF, bq[nt], acc[mt][nt], 0, 0, 0);
        }
    }

    // ---- epilogue: D[m = q*4+reg][n = l15]; 8-way k-split -> atomicAdd ----
    const int h = h0 + wave;
#pragma unroll
    for (int mt = 0; mt < 2; ++mt) {
#pragma unroll
        for (int nt = 0; nt < 4; ++nt) {
            const int oc = nt * 16 + l15;
            float* op = out + ((size_t)(b * COUT + oc) * HH + h) * WW + mt * 16 + q * 4;
#pragma unroll
            for (int reg = 0; reg < 4; ++reg)
                atomicAdd(op + reg, acc[mt][nt][reg]);
        }
    }
}

extern "C" void kernel_launch(void* const* d_in, const int* in_sizes, int n_in,
                              void* d_out, int out_size, void* d_ws, size_t ws_size,
                              hipStream_t stream) {
    const float* x  = (const float*)d_in[0];
    const float* sw = (const float*)d_in[1];
    const float* sc = (const float*)d_in[2];
    float* out = (float*)d_out;
    short* W3 = (short*)d_ws;   // 294,912 bf16 = 576 KB

    zero_kernel<<<(out_size / 4 + 255) / 256, 256, 0, stream>>>((float4*)out);
    wt_kernel<<<(294912 + 255) / 256, 256, 0, stream>>>(sw, sc, W3);
    conv_kernel<<<1024, 256, 0, stream>>>(x, W3, out);
}

// Round 4
// 95.230 us; speedup vs baseline: 1.8668x; 1.8668x over previous
//
#include <hip/hip_runtime.h>

#define CINC 64
#define COUT 64
#define HH 32
#define WW 32
#define BB 16
#define NSPLIT 4
#define CPS 16            // cin per split

typedef __attribute__((ext_vector_type(8))) short short8;
typedef __attribute__((ext_vector_type(4))) float floatx4;

__device__ __forceinline__ unsigned short f2bf(float f) {
    union { float f; unsigned int u; } c; c.f = f;
    unsigned int r = (c.u + 0x7FFFu + ((c.u >> 16) & 1u)) >> 16;
    return (unsigned short)r;
}

// W3 layout: [split(4)][tap(9)][s(4)][oc(64)][q(4)][e(8)] bf16
// k = s*32 + q*8 + e (0..127), cin = split*16 + k/8, g = k%8
__global__ __launch_bounds__(256) void wt_kernel(const float* __restrict__ sw,
                                                 const float* __restrict__ sc,
                                                 short* __restrict__ W3) {
    int idx = blockIdx.x * blockDim.x + threadIdx.x;
    const int total = NSPLIT * 9 * 4 * 64 * 4 * 8;   // 294,912
    if (idx >= total) return;
    int e = idx & 7;
    int q = (idx >> 3) & 3;
    int oc = (idx >> 5) & 63;
    int s = (idx >> 11) & 3;
    int tap = (idx >> 13) % 9;
    int split = (idx >> 13) / 9;
    int k = s * 32 + q * 8 + e;
    int cin = split * CPS + (k >> 3);
    int g = k & 7;
    int kh = tap / 3, kw = tap % 3;
    float w = sw[(((oc * CINC + cin) * 8 + g) * 3 + kh) * 3 + kw] * sc[oc * CINC + cin];
    W3[idx] = (short)f2bf(w);
}

// out = sum of 4 partials (float4-vectorized, fully coalesced)
__global__ __launch_bounds__(256) void reduce_kernel(const floatx4* __restrict__ p,
                                                     floatx4* __restrict__ out) {
    int idx = blockIdx.x * blockDim.x + threadIdx.x;
    const int n4 = BB * COUT * HH * WW / 4;          // 262,144
    if (idx >= n4) return;
    const int stride = BB * COUT * HH * WW / 4;
    out[idx] = p[idx] + p[idx + stride] + p[idx + 2 * stride] + p[idx + 3 * stride];
}

// Fused bases + implicit-GEMM conv, no atomics.
// Grid: 1024 = 256 m-blocks x 4 splits (split = bid&3). Block: 4 waves.
// m-block: batch b, output rows h0..h0+1 (64 px). Wave: row h0+(wave>>1), oc half (wave&1)*32.
__global__ __launch_bounds__(256, 4) void conv_kernel(const float* __restrict__ xin,
                                                      const short* __restrict__ W3,
                                                      float* __restrict__ partial) {
    __shared__ short A[4 * 34 * 128];   // 34,816 B: [r(4)][x(34)][slot(16)][e(8)], slot=cl^(x&15)

    const int split = blockIdx.x & 3;
    const int mb = blockIdx.x >> 2;
    const int b = mb >> 4;
    const int h0 = (mb & 15) * 2;
    const int t = threadIdx.x;
    const int wave = t >> 6;
    const int lane = t & 63;
    const int l15 = lane & 15;
    const int q = lane >> 4;
    const int rowl = wave >> 1;
    const int n0 = (wave & 1) * 32;
    const int cin0 = split * CPS;

    // ---- prefetch first B fragments (no LDS dependency) ----
    const short* Wb = W3 + (size_t)split * 36 * 2048;
    short8 bq[2], bqn[2];
#pragma unroll
    for (int nt = 0; nt < 2; ++nt)
        bqn[nt] = *(const short8*)(Wb + (n0 + nt * 16 + l15) * 32 + q * 8);

    // ---- stage A: closed-form uniform cubic B-spline bases -> bf16 LDS ----
    for (int u = t; u < 4 * 34 * CPS; u += 256) {     // 2176 items, x-innermost
        int x34 = u % 34;
        int rc = u / 34;
        int cl = rc & 15;
        int r = rc >> 4;
        int y = h0 + r;
        float v = 0.0f;
        if (y >= 1 && y <= HH && x34 >= 1 && x34 <= WW)
            v = xin[((b * CINC + cin0 + cl) * HH + (y - 1)) * WW + (x34 - 1)];
        float sv = fmaf(v, 2.5f, 5.5f);               // (v + 2.2) / 0.4
        float cf = floorf(sv);
        int c = (int)cf;
        float f = sv - cf;
        float f2 = f * f, f3 = f2 * f;
        float omf = 1.0f - f;
        float w0 = f3 * (1.0f / 6.0f);
        float w1 = (1.0f + 3.0f * f + 3.0f * f2 - 3.0f * f3) * (1.0f / 6.0f);
        float w2 = (4.0f - 6.0f * f2 + 3.0f * f3) * (1.0f / 6.0f);
        float w3 = (omf * omf * omf) * (1.0f / 6.0f);
        short o8[8];
#pragma unroll
        for (int j = 0; j < 8; ++j) {
            float bj = (j == c) ? w0 : (j == c - 1) ? w1 : (j == c - 2) ? w2
                       : (j == c - 3) ? w3 : 0.0f;
            o8[j] = (short)f2bf(bj);
        }
        *(int4*)&A[(r * 34 + x34) * 128 + ((cl ^ (x34 & 15)) * 8)] = *(const int4*)o8;
    }
    __syncthreads();

    floatx4 acc[2][2];
#pragma unroll
    for (int mt = 0; mt < 2; ++mt)
#pragma unroll
        for (int nt = 0; nt < 2; ++nt) acc[mt][nt] = (floatx4)0.f;

    // ---- main loop: 36 steps = 9 taps x 4 k-quarters, 1-step B prefetch ----
#pragma unroll
    for (int ts = 0; ts < 36; ++ts) {
        const int tap = ts >> 2, s = ts & 3;
        const int kh = tap / 3, kw = tap % 3;
#pragma unroll
        for (int nt = 0; nt < 2; ++nt) bq[nt] = bqn[nt];
        if (ts < 35) {
            const short* wp = Wb + (size_t)(ts + 1) * 2048;
#pragma unroll
            for (int nt = 0; nt < 2; ++nt)
                bqn[nt] = *(const short8*)(wp + (n0 + nt * 16 + l15) * 32 + q * 8);
        }
#pragma unroll
        for (int mt = 0; mt < 2; ++mt) {
            const int xi = mt * 16 + l15 + kw;
            short8 aF = *(const short8*)&A[((rowl + kh) * 34 + xi) * 128 +
                                           (((s * 4 + q) ^ (xi & 15)) * 8)];
#pragma unroll
            for (int nt = 0; nt < 2; ++nt)
                acc[mt][nt] = __builtin_amdgcn_mfma_f32_16x16x32_bf16(aF, bq[nt], acc[mt][nt], 0, 0, 0);
        }
    }

    // ---- epilogue: plain float4 stores to this split's partial buffer ----
    const int h = h0 + rowl;
#pragma unroll
    for (int mt = 0; mt < 2; ++mt) {
#pragma unroll
        for (int nt = 0; nt < 2; ++nt) {
            const int oc = n0 + nt * 16 + l15;
            float* op = partial + ((((size_t)split * BB + b) * COUT + oc) * HH + h) * WW
                        + mt * 16 + q * 4;
            *(floatx4*)op = acc[mt][nt];
        }
    }
}

extern "C" void kernel_launch(void* const* d_in, const int* in_sizes, int n_in,
                              void* d_out, int out_size, void* d_ws, size_t ws_size,
                              hipStream_t stream) {
    const float* x  = (const float*)d_in[0];
    const float* sw = (const float*)d_in[1];
    const float* sc = (const float*)d_in[2];
    float* out = (float*)d_out;
    short* W3 = (short*)d_ws;                           // 294,912 bf16 = 576 KB
    float* partial = (float*)((char*)d_ws + 294912 * 2); // 4 x 4 MB fp32 partials

    wt_kernel<<<(294912 + 255) / 256, 256, 0, stream>>>(sw, sc, W3);
    conv_kernel<<<1024, 256, 0, stream>>>(x, W3, partial);
    reduce_kernel<<<(out_size / 4 + 255) / 256, 256, 0, stream>>>(
        (const floatx4*)partial, (floatx4*)out);
}